// Round 13
// baseline (31.308 us; speedup 1.0000x reference)
//
#include <hip/hip_runtime.h>
#include <hip/hip_bf16.h>

typedef __attribute__((ext_vector_type(8))) short short8;   // 8 bf16 (4 VGPRs)
typedef __attribute__((ext_vector_type(4))) float f32x4;    // MFMA acc

#define NPTS 131072

__device__ inline unsigned short f2bf(float f) {
    unsigned u = __float_as_uint(f);
    u = (u + 0x7FFFu + ((u >> 16) & 1u)) >> 16;   // RNE
    return (unsigned short)u;
}

__device__ inline unsigned pack2(float a, float b) {
    union { __hip_bfloat162 h; unsigned u; } v;
    v.h = __float22bfloat162_rn(float2{a, b});    // v_cvt_pk_bf16_f32 (RNE)
    return v.u;
}

__device__ inline float bflo(unsigned u) { return __uint_as_float(u << 16); }
__device__ inline float bfhi(unsigned u) { return __uint_as_float(u & 0xffff0000u); }

// ---------------- prep: weight tables + bones4 + bf16 qcf rows --------------
// w1t[e][k] ; w2t[e][pi(d)] ; beff ; w3t[q][k] (sigma) ; bones4 {x,y,z,0} ;
// qbf[row][8 u32] = bf16-packed qcf row (32 B). Sections R11-green + qbf.
__global__ __launch_bounds__(256) void prep_kernel(
    const float* __restrict__ Ws, const float* __restrict__ bs,
    const float* __restrict__ W1, const float* __restrict__ b1,
    const float* __restrict__ W2, const float* __restrict__ W3,
    const float* __restrict__ bones, const float* __restrict__ qcf,
    unsigned short* __restrict__ w1t, unsigned short* __restrict__ w2t,
    float* __restrict__ beff, unsigned short* __restrict__ w3t,
    float* __restrict__ bones4, unsigned* __restrict__ qbf)
{
    int t = blockIdx.x * 256 + threadIdx.x;
    if (t < 4096) {
        int e = t >> 5, k = t & 31;
        float v = 0.f;
        if (k < 16) {
#pragma unroll 16
            for (int d = 0; d < 128; ++d) v = fmaf(Ws[k*128 + d], W1[d*128 + e], v);
        } else if (k < 19) {
            v = W1[(128 + (k - 16))*128 + e];
        }
        w1t[e*32 + k] = f2bf(v);
    } else if (t < 8192) {
        int t2 = t - 4096;
        int e = t2 >> 7, d = t2 & 127;
        w2t[e*128 + ((d & 15)*8 + (d >> 4))] = f2bf(W2[d*32 + e]);
    } else if (t < 8320) {
        int e = t - 8192;
        float v = b1[e];
#pragma unroll 16
        for (int d = 0; d < 128; ++d) v = fmaf(bs[d], W1[d*128 + e], v);
        beff[e] = v;
    } else if (t < 8832) {
        int i = t - 8320;
        int q = i >> 5, k = i & 31;
        int e = (k & 1)*16 + (k >> 1);        // sigma^-1(k)
        int r = e >> 3, f = e & 7;
        float v = 0.f;
        if (q < 12) {
            int r2 = q / 3, o = q - r2*3;
            if (r == r2) v = W3[f*3 + o];
        }
        w3t[q*32 + k] = f2bf(v);
    } else if (t < 17024) {
        int i = t - 8832;                     // one bone row per thread
        float4 v;
        v.x = bones[i*3 + 0];
        v.y = bones[i*3 + 1];
        v.z = bones[i*3 + 2];
        v.w = 0.f;
        ((float4*)bones4)[i] = v;
    } else if (t < 25216) {
        int row = t - 17024;                  // one qcf row per thread
        const float4* q = (const float4*)(qcf + row*16);
        const float4 q0 = q[0], q1 = q[1], q2 = q[2], q3 = q[3];
        uint4 o0, o1;
        o0.x = pack2(q0.x, q0.y); o0.y = pack2(q0.z, q0.w);
        o0.z = pack2(q1.x, q1.y); o0.w = pack2(q1.z, q1.w);
        o1.x = pack2(q2.x, q2.y); o1.y = pack2(q2.z, q2.w);
        o1.z = pack2(q3.x, q3.y); o1.w = pack2(q3.z, q3.w);
        ((uint4*)qbf)[row*2 + 0] = o0;
        ((uint4*)qbf)[row*2 + 1] = o1;
    }
}

// ---------------- decoder: row-gather front-end + R10-green MFMA back-end ---
// 4 waves/block, one 16-pt tile per wave, grid 2048.
// Per-wave LDS: Xbu 16x8 u32 = 512 B ; H1b 16x136 bf16 = 4352 B ;
//               H2p 16x40 bf16 = 1280 B  -> WREG = 6144 B
#define WREG 6144

// lane = (point-group pgrp, neighbor k). Returns this lane's 2 summed channels
// {2k, 2k+1} of the IDW-interpolated bf16 qcf row for point pgrp.
__device__ __forceinline__ float2 interp_pass(
    int idxv, float4 bb, float wxx, float wyy, float wzz, int k,
    const unsigned* __restrict__ qbf)
{
    // qcf row (issued early; no dependence on dist math)
    const uint4 ra = *(const uint4*)(qbf + idxv*8);
    const uint4 rb = *(const uint4*)(qbf + idxv*8 + 4);

    const float rx = wxx - bb.x, ry = wyy - bb.y, rz = wzz - bb.z;
    const float dist = sqrtf(fmaf(rx,rx, fmaf(ry,ry, fmaf(rz,rz, 1e-8f))));
    const float w = 1.0f / (dist + 1e-8f);
    float s = w;
    s += __shfl_xor(s, 1);
    s += __shfl_xor(s, 2);
    s += __shfl_xor(s, 4);
    const float wn = w / s;

    float v[16];
    v[ 0] = wn*bflo(ra.x); v[ 1] = wn*bfhi(ra.x);
    v[ 2] = wn*bflo(ra.y); v[ 3] = wn*bfhi(ra.y);
    v[ 4] = wn*bflo(ra.z); v[ 5] = wn*bfhi(ra.z);
    v[ 6] = wn*bflo(ra.w); v[ 7] = wn*bfhi(ra.w);
    v[ 8] = wn*bflo(rb.x); v[ 9] = wn*bfhi(rb.x);
    v[10] = wn*bflo(rb.y); v[11] = wn*bfhi(rb.y);
    v[12] = wn*bflo(rb.z); v[13] = wn*bfhi(rb.z);
    v[14] = wn*bflo(rb.w); v[15] = wn*bfhi(rb.w);

    // 3-round keep/send butterfly over the 8 neighbor lanes.
    // After round r each lane holds the k-sum of a halved channel block;
    // final: v[0],v[1] = channels {2k, 2k+1}.
#pragma unroll
    for (int j = 0; j < 8; ++j) {
        const float sv = (k & 4) ? v[j] : v[j + 8];
        const float t  = __shfl_xor(sv, 4);
        v[j] = ((k & 4) ? v[j + 8] : v[j]) + t;
    }
#pragma unroll
    for (int j = 0; j < 4; ++j) {
        const float sv = (k & 2) ? v[j] : v[j + 4];
        const float t  = __shfl_xor(sv, 2);
        v[j] = ((k & 2) ? v[j + 4] : v[j]) + t;
    }
#pragma unroll
    for (int j = 0; j < 2; ++j) {
        const float sv = (k & 1) ? v[j] : v[j + 2];
        const float t  = __shfl_xor(sv, 1);
        v[j] = ((k & 1) ? v[j + 2] : v[j]) + t;
    }
    return float2{ v[0], v[1] };
}

__global__ __launch_bounds__(256, 2) void decoder_kernel(
    const unsigned* __restrict__ qbf, const int* __restrict__ didx,
    const float* __restrict__ dwin, const float* __restrict__ bones4,
    const unsigned short* __restrict__ w1t, const unsigned short* __restrict__ w2t,
    const float* __restrict__ beff, const float* __restrict__ b2,
    const unsigned short* __restrict__ w3t, const float* __restrict__ b3,
    float* __restrict__ out)
{
    __shared__ unsigned char lds[4 * WREG];

    const int tid  = threadIdx.x;
    const int wave = tid >> 6;
    const int lane = tid & 63;
    unsigned char* wbase = lds + wave * WREG;
    unsigned*       Xbu = (unsigned*)(wbase);
    unsigned short* H1b = (unsigned short*)(wbase + 512);
    unsigned short* H2p = (unsigned short*)(wbase + 512 + 4352);

    const int q4  = lane >> 4;
    const int l16 = lane & 15;

    const int gw   = blockIdx.x * 4 + wave;
    const int base = gw * 16;

    // ---- phase A: gather + IDW + interp, lane = (point-group, neighbor) ----
    const int pgrp = lane >> 3;          // 0..7
    const int k    = lane & 7;           // neighbor slot
    const int p0   = base + pgrp;        // pass-0 point
    const int p1   = base + 8 + pgrp;    // pass-1 point

    const int i0 = didx[p0*8 + k];
    const int i1 = didx[p1*8 + k];
    const float4* __restrict__ bn4 = (const float4*)bones4;
    const float4 bb0 = bn4[i0];
    const float4 bb1 = bn4[i1];
    const float wx0 = dwin[p0*3+0], wy0 = dwin[p0*3+1], wz0 = dwin[p0*3+2];
    const float wx1 = dwin[p1*3+0], wy1 = dwin[p1*3+1], wz1 = dwin[p1*3+2];

    // A-frag window components + residuals (lane-as-point addressing)
    const float wxA = dwin[(base + l16)*3 + 0];
    const float wyA = dwin[(base + l16)*3 + 1];
    const float wzA = dwin[(base + l16)*3 + 2];
    const int o3c = l16 - (l16/3)*3;
    float rw0 = 0.f, rw1 = 0.f, rw2 = 0.f, rw3 = 0.f;
    if (l16 < 12) {
        rw0 = dwin[(size_t)(base + q4*4 + 0)*3 + o3c];
        rw1 = dwin[(size_t)(base + q4*4 + 1)*3 + o3c];
        rw2 = dwin[(size_t)(base + q4*4 + 2)*3 + o3c];
        rw3 = dwin[(size_t)(base + q4*4 + 3)*3 + o3c];
    }

    const float2 x0 = interp_pass(i0, bb0, wx0, wy0, wz0, k, qbf);
    const float2 x1 = interp_pass(i1, bb1, wx1, wy1, wz1, k, qbf);
    Xbu[pgrp*8 + k]       = pack2(x0.x, x0.y);   // ch {2k,2k+1} of point pgrp
    Xbu[(8 + pgrp)*8 + k] = pack2(x1.x, x1.y);

    // ---- hoisted weight fragments (off critical path) ----------------------
    short8 W1f[8]; float beffv[8];
#pragma unroll
    for (int dt = 0; dt < 8; ++dt) {
        W1f[dt]   = *(const short8*)(w1t + (dt*16 + l16)*32 + q4*8);
        beffv[dt] = beff[dt*16 + l16];
    }
    short8 W2f[2][4]; float b2v[2];
#pragma unroll
    for (int et = 0; et < 2; ++et) {
        b2v[et] = b2[et*16 + l16];
#pragma unroll
        for (int kt = 0; kt < 4; ++kt)
            W2f[et][kt] = *(const short8*)(w2t + (et*16 + l16)*128 + kt*32 + q4*8);
    }
    const short8 w3f = *(const short8*)(w3t + l16*32 + q4*8);
    const float  b3o = (l16 < 12) ? b3[o3c] : 0.f;

    __syncthreads();

    // ---- A-fragment: lane(point l16) x channels q4*8..+7 -------------------
    union { uint4 v; short8 s8; } a1u;
    a1u.v = uint4{0u, 0u, 0u, 0u};
    if (q4 < 2) {
        a1u.v = *(const uint4*)(Xbu + l16*8 + q4*4);
    } else if (q4 == 2) {
        a1u.v.x = pack2(wxA, wyA);
        a1u.v.y = pack2(wzA, 0.f);
    }

    // ---- layer 1: [16x32] @ [32x128] via 8 MFMA ----------------------------
    f32x4 acc1[8];
#pragma unroll
    for (int dt = 0; dt < 8; ++dt) {
        f32x4 c = { beffv[dt], beffv[dt], beffv[dt], beffv[dt] };
        acc1[dt] = __builtin_amdgcn_mfma_f32_16x16x32_bf16(a1u.s8, W1f[dt], c, 0, 0, 0);
    }
    // relu + pack to pi-permuted H1: lane owns cols l16*8+dt -> 4x b128 write
#pragma unroll
    for (int r = 0; r < 4; ++r) {
        union { unsigned u[4]; short8 s8; } pk;
        pk.u[0] = pack2(fmaxf(acc1[0][r],0.f), fmaxf(acc1[1][r],0.f));
        pk.u[1] = pack2(fmaxf(acc1[2][r],0.f), fmaxf(acc1[3][r],0.f));
        pk.u[2] = pack2(fmaxf(acc1[4][r],0.f), fmaxf(acc1[5][r],0.f));
        pk.u[3] = pack2(fmaxf(acc1[6][r],0.f), fmaxf(acc1[7][r],0.f));
        *(short8*)(H1b + (q4*4 + r)*136 + l16*8) = pk.s8;
    }
    __syncthreads();

    // ---- layer 2: [16x128] @ [128x32] via 8 MFMA (pi-space K) --------------
    f32x4 acc2[2] = { { b2v[0], b2v[0], b2v[0], b2v[0] },
                      { b2v[1], b2v[1], b2v[1], b2v[1] } };
#pragma unroll
    for (int kt = 0; kt < 4; ++kt) {
        const short8 a2 = *(const short8*)(H1b + l16*136 + kt*32 + q4*8);
        acc2[0] = __builtin_amdgcn_mfma_f32_16x16x32_bf16(a2, W2f[0][kt], acc2[0], 0, 0, 0);
        acc2[1] = __builtin_amdgcn_mfma_f32_16x16x32_bf16(a2, W2f[1][kt], acc2[1], 0, 0, 0);
    }
    // relu + pack to sigma-permuted H2: lane owns cols l16*2+et
#pragma unroll
    for (int r = 0; r < 4; ++r) {
        unsigned p01 = pack2(fmaxf(acc2[0][r],0.f), fmaxf(acc2[1][r],0.f));
        *(unsigned*)(H2p + (q4*4 + r)*40 + l16*2) = p01;
    }
    __syncthreads();

    // ---- layer 3: [16x32] @ [32x12] via 1 MFMA + residual ------------------
    const short8 a3 = *(const short8*)(H2p + l16*40 + q4*8);
    f32x4 c3 = { b3o, b3o, b3o, b3o };
    f32x4 o3 = __builtin_amdgcn_mfma_f32_16x16x32_bf16(a3, w3f, c3, 0, 0, 0);
    if (l16 < 12) {
        out[(size_t)(base + q4*4 + 0)*12 + l16] = rw0 + o3[0];
        out[(size_t)(base + q4*4 + 1)*12 + l16] = rw1 + o3[1];
        out[(size_t)(base + q4*4 + 2)*12 + l16] = rw2 + o3[2];
        out[(size_t)(base + q4*4 + 3)*12 + l16] = rw3 + o3[3];
    }
}

extern "C" void kernel_launch(void* const* d_in, const int* in_sizes, int n_in,
                              void* d_out, int out_size, void* d_ws, size_t ws_size,
                              hipStream_t stream) {
    const float* qcf   = (const float*)d_in[0];
    const int*   didx  = (const int*)  d_in[1];
    const float* dwin  = (const float*)d_in[2];
    const float* bones = (const float*)d_in[3];
    // d_in[4] = K (always 8)
    const float* Ws = (const float*)d_in[5];
    const float* bs = (const float*)d_in[6];
    const float* W1 = (const float*)d_in[7];
    const float* b1 = (const float*)d_in[8];
    const float* W2 = (const float*)d_in[9];
    const float* b2 = (const float*)d_in[10];
    const float* W3 = (const float*)d_in[11];
    const float* b3 = (const float*)d_in[12];
    float* out = (float*)d_out;

    unsigned short* w1t    = (unsigned short*)d_ws;                    // 8 KB
    unsigned short* w2t    = (unsigned short*)((char*)d_ws + 8192);    // 8 KB
    float*          beff   = (float*)((char*)d_ws + 16384);            // 512 B
    unsigned short* w3t    = (unsigned short*)((char*)d_ws + 16896);   // 1 KB
    float*          bones4 = (float*)((char*)d_ws + 17920);            // 128 KB
    unsigned*       qbf    = (unsigned*)((char*)d_ws + 163840);        // 256 KB

    hipLaunchKernelGGL(prep_kernel, dim3(99), dim3(256), 0, stream,
                       Ws, bs, W1, b1, W2, W3, bones, qcf,
                       w1t, w2t, beff, w3t, bones4, qbf);
    hipLaunchKernelGGL(decoder_kernel, dim3(2048), dim3(256), 0, stream,
                       qbf, didx, dwin, bones4, w1t, w2t, beff, b2, w3t, b3, out);
}